// Round 3
// baseline (190.699 us; speedup 1.0000x reference)
//
#include <hip/hip_runtime.h>

#define NUM_ROI 148
#define NQ 5
#define NN 131072
#define NSEG 8
#define SEGF (NN / NSEG)          // 16384 floats = 64 KB per row-segment
#define ITERS (SEGF / (256 * 4))  // 16

// One block per (roi, n-segment). roi is block-uniform -> weights are scalar
// (s_load) broadcasts; no LDS, no barrier. Each block streams TWO long
// contiguous write ranges (r-row and f-row, 64 KB each) instead of the old
// 4KB-burst / 512KB-stride pattern that killed HBM page locality.
// Z/X are tiny (3 MB) and L2-resident; re-reading them per roi costs ~13 us
// of L2 traffic that overlaps the HBM writes.
__global__ __launch_bounds__(256) void coconet_kernel(
    const float* __restrict__ X, const float* __restrict__ Z,
    const float* __restrict__ Wr, const float* __restrict__ br,
    const float* __restrict__ Wf, const float* __restrict__ bf,
    float* __restrict__ out)
{
    const int roi = blockIdx.y;
    const int tid = threadIdx.x;
    const int nbase = blockIdx.x * SEGF + tid * 4;

    // Block-uniform weight loads (SGPR).
    const float wr0 = Wr[roi * NQ + 0], wr1 = Wr[roi * NQ + 1],
                wr2 = Wr[roi * NQ + 2], wr3 = Wr[roi * NQ + 3],
                wr4 = Wr[roi * NQ + 4];
    const float brv = br[roi];
    const float wfx = Wf[roi * 6 + 0];
    const float wf0 = Wf[roi * 6 + 1], wf1 = Wf[roi * 6 + 2],
                wf2 = Wf[roi * 6 + 3], wf3 = Wf[roi * 6 + 4],
                wf4 = Wf[roi * 6 + 5];
    const float bfv = bf[roi];

    float* oR = out + (size_t)roi * NN + nbase;
    float* oF = out + (size_t)(NUM_ROI + roi) * NN + nbase;

    #pragma unroll 4
    for (int it = 0; it < ITERS; ++it) {
        const int n = nbase + it * 1024;  // block advances 4 KB per iter

        // Z rows n..n+3: 20 contiguous floats, 16B-aligned (n % 4 == 0)
        const float4* zp = reinterpret_cast<const float4*>(Z + (size_t)n * NQ);
        const float4 a = zp[0], b2 = zp[1], c = zp[2], d = zp[3], e = zp[4];
        const float4 x4 = *reinterpret_cast<const float4*>(X + n);
        const float x[4] = {x4.x, x4.y, x4.z, x4.w};
        const float t[20] = {a.x,  a.y,  a.z,  a.w,  b2.x, b2.y, b2.z, b2.w,
                             c.x,  c.y,  c.z,  c.w,  d.x,  d.y,  d.z,  d.w,
                             e.x,  e.y,  e.z,  e.w};

        float rr[4], ff[4];
        #pragma unroll
        for (int j = 0; j < 4; ++j) {
            const float z0 = t[j * 5 + 0], z1 = t[j * 5 + 1],
                        z2 = t[j * 5 + 2], z3 = t[j * 5 + 3],
                        z4 = t[j * 5 + 4];
            float r_ = brv;
            float f_ = fmaf(x[j], wfx, bfv);
            r_ = fmaf(z0, wr0, r_);  f_ = fmaf(z0, wf0, f_);
            r_ = fmaf(z1, wr1, r_);  f_ = fmaf(z1, wf1, f_);
            r_ = fmaf(z2, wr2, r_);  f_ = fmaf(z2, wf2, f_);
            r_ = fmaf(z3, wr3, r_);  f_ = fmaf(z3, wf3, f_);
            r_ = fmaf(z4, wr4, r_);  f_ = fmaf(z4, wf4, f_);
            rr[j] = r_;
            ff[j] = f_;
        }
        *reinterpret_cast<float4*>(oR + it * 1024) =
            make_float4(rr[0], rr[1], rr[2], rr[3]);
        *reinterpret_cast<float4*>(oF + it * 1024) =
            make_float4(ff[0], ff[1], ff[2], ff[3]);
    }
}

extern "C" void kernel_launch(void* const* d_in, const int* in_sizes, int n_in,
                              void* d_out, int out_size, void* d_ws, size_t ws_size,
                              hipStream_t stream) {
    const float* X  = (const float*)d_in[0];
    const float* Z  = (const float*)d_in[1];
    const float* Wr = (const float*)d_in[2];
    const float* br = (const float*)d_in[3];
    const float* Wf = (const float*)d_in[4];
    const float* bf = (const float*)d_in[5];
    float* out = (float*)d_out;

    dim3 grid(NSEG, NUM_ROI);  // 8 x 148 = 1184 blocks, ~18.5 waves/CU
    coconet_kernel<<<grid, 256, 0, stream>>>(X, Z, Wr, br, Wf, bf, out);
}

// Round 5
// 177.871 us; speedup vs baseline: 1.0721x; 1.0721x over previous
//
#include <hip/hip_runtime.h>

#define NUM_ROI 148
#define NQ 5
#define NN 131072
#define NSEG 16
#define SEGF (NN / NSEG)          // 8192 floats = 32 KB per row-segment
#define ITERS (SEGF / (256 * 4))  // 8

// One block per (roi, n-segment); roi block-uniform -> weights in SGPRs.
// Each block streams TWO contiguous 32 KB write ranges (r-row, f-row).
// SPILL-PROOF rewrite of R3: no intermediate arrays -- float4 components
// consumed directly as scalars, so everything stays in registers.
__global__ __launch_bounds__(256) void coconet_kernel(
    const float* __restrict__ X, const float* __restrict__ Z,
    const float* __restrict__ Wr, const float* __restrict__ br,
    const float* __restrict__ Wf, const float* __restrict__ bf,
    float* __restrict__ out)
{
    const int roi = blockIdx.y;
    const int tid = threadIdx.x;
    const int nbase = blockIdx.x * SEGF + tid * 4;

    // Block-uniform weight loads -> SGPR broadcasts.
    const float wr0 = Wr[roi * NQ + 0], wr1 = Wr[roi * NQ + 1],
                wr2 = Wr[roi * NQ + 2], wr3 = Wr[roi * NQ + 3],
                wr4 = Wr[roi * NQ + 4];
    const float brv = br[roi];
    const float wfx = Wf[roi * 6 + 0];
    const float wf0 = Wf[roi * 6 + 1], wf1 = Wf[roi * 6 + 2],
                wf2 = Wf[roi * 6 + 3], wf3 = Wf[roi * 6 + 4],
                wf4 = Wf[roi * 6 + 5];
    const float bfv = bf[roi];

    float* oR = out + (size_t)roi * NN + nbase;
    float* oF = out + (size_t)(NUM_ROI + roi) * NN + nbase;

    #pragma unroll 2
    for (int it = 0; it < ITERS; ++it) {
        const int n = nbase + it * 1024;  // block advances 4 KB per iter

        // Z rows n..n+3: 20 contiguous floats (16B-aligned, n % 4 == 0).
        const float4* zp = reinterpret_cast<const float4*>(Z + (size_t)n * NQ);
        const float4 za = zp[0];  // z[0].{0,1,2,3}
        const float4 zb = zp[1];  // z[0].4, z[1].{0,1,2}
        const float4 zc = zp[2];  // z[1].{3,4}, z[2].{0,1}
        const float4 zd = zp[3];  // z[2].{2,3,4}, z[3].0
        const float4 ze = zp[4];  // z[3].{1,2,3,4}
        const float4 x4 = *reinterpret_cast<const float4*>(X + n);

        float4 rv, fv;

        // j = 0: z = za.x za.y za.z za.w zb.x
        {
            float r_ = brv, f_ = fmaf(x4.x, wfx, bfv);
            r_ = fmaf(za.x, wr0, r_);  f_ = fmaf(za.x, wf0, f_);
            r_ = fmaf(za.y, wr1, r_);  f_ = fmaf(za.y, wf1, f_);
            r_ = fmaf(za.z, wr2, r_);  f_ = fmaf(za.z, wf2, f_);
            r_ = fmaf(za.w, wr3, r_);  f_ = fmaf(za.w, wf3, f_);
            r_ = fmaf(zb.x, wr4, r_);  f_ = fmaf(zb.x, wf4, f_);
            rv.x = r_;  fv.x = f_;
        }
        // j = 1: z = zb.y zb.z zb.w zc.x zc.y
        {
            float r_ = brv, f_ = fmaf(x4.y, wfx, bfv);
            r_ = fmaf(zb.y, wr0, r_);  f_ = fmaf(zb.y, wf0, f_);
            r_ = fmaf(zb.z, wr1, r_);  f_ = fmaf(zb.z, wf1, f_);
            r_ = fmaf(zb.w, wr2, r_);  f_ = fmaf(zb.w, wf2, f_);
            r_ = fmaf(zc.x, wr3, r_);  f_ = fmaf(zc.x, wf3, f_);
            r_ = fmaf(zc.y, wr4, r_);  f_ = fmaf(zc.y, wf4, f_);
            rv.y = r_;  fv.y = f_;
        }
        // j = 2: z = zc.z zc.w zd.x zd.y zd.z
        {
            float r_ = brv, f_ = fmaf(x4.z, wfx, bfv);
            r_ = fmaf(zc.z, wr0, r_);  f_ = fmaf(zc.z, wf0, f_);
            r_ = fmaf(zc.w, wr1, r_);  f_ = fmaf(zc.w, wf1, f_);
            r_ = fmaf(zd.x, wr2, r_);  f_ = fmaf(zd.x, wf2, f_);
            r_ = fmaf(zd.y, wr3, r_);  f_ = fmaf(zd.y, wf3, f_);
            r_ = fmaf(zd.z, wr4, r_);  f_ = fmaf(zd.z, wf4, f_);
            rv.z = r_;  fv.z = f_;
        }
        // j = 3: z = zd.w ze.x ze.y ze.z ze.w
        {
            float r_ = brv, f_ = fmaf(x4.w, wfx, bfv);
            r_ = fmaf(zd.w, wr0, r_);  f_ = fmaf(zd.w, wf0, f_);
            r_ = fmaf(ze.x, wr1, r_);  f_ = fmaf(ze.x, wf1, f_);
            r_ = fmaf(ze.y, wr2, r_);  f_ = fmaf(ze.y, wf2, f_);
            r_ = fmaf(ze.z, wr3, r_);  f_ = fmaf(ze.z, wf3, f_);
            r_ = fmaf(ze.w, wr4, r_);  f_ = fmaf(ze.w, wf4, f_);
            rv.w = r_;  fv.w = f_;
        }

        *reinterpret_cast<float4*>(oR + it * 1024) = rv;
        *reinterpret_cast<float4*>(oF + it * 1024) = fv;
    }
}

extern "C" void kernel_launch(void* const* d_in, const int* in_sizes, int n_in,
                              void* d_out, int out_size, void* d_ws, size_t ws_size,
                              hipStream_t stream) {
    const float* X  = (const float*)d_in[0];
    const float* Z  = (const float*)d_in[1];
    const float* Wr = (const float*)d_in[2];
    const float* br = (const float*)d_in[3];
    const float* Wf = (const float*)d_in[4];
    const float* bf = (const float*)d_in[5];
    float* out = (float*)d_out;

    dim3 grid(NSEG, NUM_ROI);  // 16 x 148 = 2368 blocks
    coconet_kernel<<<grid, 256, 0, stream>>>(X, Z, Wr, br, Wf, bf, out);
}

// Round 6
// 162.953 us; speedup vs baseline: 1.1703x; 1.0915x over previous
//
#include <hip/hip_runtime.h>

#define NUM_ROI 148
#define NQ 5
#define NN 131072
#define ROI_SPLIT 4
#define ROI_PER (NUM_ROI / ROI_SPLIT)  // 37

// Champion structure (R0): each thread loads X/Z for its 4 n-values ONCE and
// loops over 37 ROIs (load-once reuse beats write-contiguity: R3/R5 showed
// re-reading Z per roi costs more than strided writes do). Normal stores (NT
// regressed: L2 absorbs ~32MB of the output that the next harness fill
// re-dirties in place, saving HBM drain). Grid 128x4 = 512 blocks.
__global__ __launch_bounds__(256) void coconet_kernel(
    const float* __restrict__ X, const float* __restrict__ Z,
    const float* __restrict__ Wr, const float* __restrict__ br,
    const float* __restrict__ Wf, const float* __restrict__ bf,
    float* __restrict__ out)
{
    __shared__ float w[ROI_PER][16];
    const int tid = threadIdx.x;
    const int roiBase = blockIdx.y * ROI_PER;

    if (tid < ROI_PER) {
        const int r = roiBase + tid;
        #pragma unroll
        for (int q = 0; q < NQ; ++q) w[tid][q] = Wr[r * NQ + q];
        w[tid][5] = br[r];
        #pragma unroll
        for (int d = 0; d < 6; ++d) w[tid][6 + d] = Wf[r * 6 + d];
        w[tid][12] = bf[r];
    }
    __syncthreads();

    const int n0 = (blockIdx.x * 256 + tid) * 4;

    // X[n0..n0+3]
    const float4 x4 = *reinterpret_cast<const float4*>(X + n0);
    const float x[4] = {x4.x, x4.y, x4.z, x4.w};

    // Z rows n0..n0+3: 20 contiguous floats starting at n0*5 (16B-aligned since n0%4==0)
    float z[4][NQ];
    {
        const float4* zp = reinterpret_cast<const float4*>(Z + (size_t)n0 * NQ);
        const float4 a = zp[0], b = zp[1], c = zp[2], d = zp[3], e = zp[4];
        const float tmp[20] = {a.x, a.y, a.z, a.w, b.x, b.y, b.z, b.w,
                               c.x, c.y, c.z, c.w, d.x, d.y, d.z, d.w,
                               e.x, e.y, e.z, e.w};
        #pragma unroll
        for (int j = 0; j < 4; ++j)
            #pragma unroll
            for (int q = 0; q < NQ; ++q) z[j][q] = tmp[j * NQ + q];
    }

    float* outR = out + (size_t)roiBase * NN + n0;
    float* outF = out + (size_t)(NUM_ROI + roiBase) * NN + n0;

    for (int i = 0; i < ROI_PER; ++i) {
        const float4 w0 = *reinterpret_cast<const float4*>(&w[i][0]);  // wr0..wr3
        const float4 w1 = *reinterpret_cast<const float4*>(&w[i][4]);  // wr4, br, wfx, wf0
        const float4 w2 = *reinterpret_cast<const float4*>(&w[i][8]);  // wf1..wf4
        const float bfv = w[i][12];
        const float wr[NQ] = {w0.x, w0.y, w0.z, w0.w, w1.x};
        const float brv = w1.y, wfx = w1.z;
        const float wf[NQ] = {w1.w, w2.x, w2.y, w2.z, w2.w};

        float rr[4], ff[4];
        #pragma unroll
        for (int j = 0; j < 4; ++j) {
            float r_ = brv;
            float f_ = fmaf(x[j], wfx, bfv);
            #pragma unroll
            for (int q = 0; q < NQ; ++q) {
                r_ = fmaf(z[j][q], wr[q], r_);
                f_ = fmaf(z[j][q], wf[q], f_);
            }
            rr[j] = r_;
            ff[j] = f_;
        }
        *reinterpret_cast<float4*>(outR) = make_float4(rr[0], rr[1], rr[2], rr[3]);
        *reinterpret_cast<float4*>(outF) = make_float4(ff[0], ff[1], ff[2], ff[3]);
        outR += NN;
        outF += NN;
    }
}

extern "C" void kernel_launch(void* const* d_in, const int* in_sizes, int n_in,
                              void* d_out, int out_size, void* d_ws, size_t ws_size,
                              hipStream_t stream) {
    const float* X  = (const float*)d_in[0];
    const float* Z  = (const float*)d_in[1];
    const float* Wr = (const float*)d_in[2];
    const float* br = (const float*)d_in[3];
    const float* Wf = (const float*)d_in[4];
    const float* bf = (const float*)d_in[5];
    float* out = (float*)d_out;

    dim3 grid(NN / (256 * 4), ROI_SPLIT);  // 128 x 4 = 512 blocks
    coconet_kernel<<<grid, 256, 0, stream>>>(X, Z, Wr, br, Wf, bf, out);
}